// Round 5
// baseline (1117.472 us; speedup 1.0000x reference)
//
#include <hip/hip_runtime.h>
#include <stdint.h>
#include <math.h>

// Match numpy's non-fused multiply-add rounding in distance/plane tests:
// a wrong argmin (or a boundary-mask flip) cascades into an O(1) output error.
// R1-R4 passed with absmax 0.0 using exactly these expression forms — keep them.
#pragma clang fp contract(off)

#define BLOCK 1024
#define NW (BLOCK / 64)
#define PT 8                    // points per thread per full-scan step (slab-major!)
#define PB 4                    // entries per thread per list-scan step (slab-major!)
#define MAX_ITERS 50
#define SOLO_CAP 2048           // below this, wave 0 finishes alone (no barriers)
#define EPS_NORM 1e-8f
#define EPS_SEP (-1e-6f)

// One block per target. No survivor bitmask: survival at iteration k is
// "dot_j < EPS_SEP for ALL previous planes j" (AND is monotone = the
// reference's cumulative mask), so full-N scans re-test against the LDS plane
// list with early exit (expected ~2 tests/point). Counts halve per cut, so
// only ~4 full-N passes happen before survivors fit the 32k LDS index list.
// R4 lesson: unrolling must be slab-major (i = (s*PT+j)*BLOCK + tid) so each
// load instruction stays wave-coalesced; consecutive-per-thread indexing made
// every lane hit its own cache line (416k bank conflicts + slower loads).
// Tail: below SOLO_CAP survivors, waves 1-15 retire and wave 0 runs all
// remaining iterations solo — wave-synchronous, zero __syncthreads.
__global__ __launch_bounds__(BLOCK) void convex_plane_kernel(
    const float* __restrict__ pc, const float* __restrict__ tg,
    float* __restrict__ out, int N, int M, int CAP, int stepsA)
{
    extern __shared__ uint32_t smem[];
    const int tid  = threadIdx.x;
    const int lane = tid & 63;
    const int wv   = tid >> 6;
    const int m    = blockIdx.x;

    float*    planes = (float*)smem;               // [MAX_ITERS*4] (a,b per iter)
    int*      list   = (int*)(planes + MAX_ITERS * 4); // [CAP]
    float*    red_d  = (float*)(list + CAP);       // [NW]
    int*      red_i  = (int*)(red_d + NW);         // [NW]
    int*      cw     = red_i + NW;                 // [NW]
    int*      bcast  = cw + NW;                    // [2] {argmin idx, count}
    int*      cnt    = bcast + 2;                  // [1] list-append cursor
    const float4* pl4 = (const float4*)planes;

    const float tx = tg[3*m+0], ty = tg[3*m+1], tz = tg[3*m+2];
    const float t2 = tx*tx + ty*ty + tz*tz;

    float* out_a = out;
    float* out_b = out + (size_t)MAX_ITERS * (size_t)M * 3;

    // cross-wave finish: lexicographic (d2,idx) argmin + count sum; {idx,count}
    // returned to ALL threads via barrier-protected bcast (race-safe).
    auto finish = [&](float dmin, int imin, int mycnt) -> int2 {
        #pragma unroll
        for (int off = 32; off > 0; off >>= 1) {
            float od = __shfl_down(dmin, off, 64);
            int   oi = __shfl_down(imin, off, 64);
            int   oc = __shfl_down(mycnt, off, 64);
            if (od < dmin || (od == dmin && oi < imin)) { dmin = od; imin = oi; }
            mycnt += oc;
        }
        if (lane == 0) { red_d[wv] = dmin; red_i[wv] = imin; cw[wv] = mycnt; }
        __syncthreads();
        if (wv == 0) {
            float bd = (lane < NW) ? red_d[lane] : INFINITY;
            int   bi = (lane < NW) ? red_i[lane] : 0;
            int   c  = (lane < NW) ? cw[lane]    : 0;
            #pragma unroll
            for (int off = 8; off > 0; off >>= 1) {
                float od = __shfl_down(bd, off, 64);
                int   oi = __shfl_down(bi, off, 64);
                int   oc = __shfl_down(c,  off, 64);
                if (od < bd || (od == bd && oi < bi)) { bd = od; bi = oi; }
                c += oc;
            }
            if (lane == 0) { bcast[0] = bi; bcast[1] = c; }
        }
        __syncthreads();
        int2 r; r.x = bcast[0]; r.y = bcast[1];
        return r;
    };

    // Full-N scan: test each point against planes[0..kplanes), argmin of d2
    // over keepers; optionally compact keepers into list (valid iff count<=CAP).
    // Slab-major: every load instruction is wave-coalesced (stride 12 B/lane).
    auto scanFull = [&](int kplanes, bool build) -> int2 {
        if (tid == 0) cnt[0] = 0;
        __syncthreads();                  // also makes planes[kplanes-1] visible
        float dmin = INFINITY;
        int   imin = 0;
        int   mycnt = 0;
        for (int s = 0; s < stepsA; ++s) {
            const int ib = s * PT * BLOCK + tid;
            float px[PT], py[PT], pz[PT];
            #pragma unroll
            for (int j = 0; j < PT; ++j) {         // issue all loads up front
                const int i = ib + j * BLOCK;
                if (i < N) {
                    const float* p = pc + 3 * (size_t)i;
                    px[j] = p[0]; py[j] = p[1]; pz[j] = p[2];
                } else { px[j] = 0.f; py[j] = 0.f; pz[j] = 0.f; }
            }
            uint32_t keepm = 0;
            #pragma unroll
            for (int j = 0; j < PT; ++j) {
                const int i = ib + j * BLOCK;
                if (i < N) {
                    bool keep = true;
                    for (int q = 0; q < kplanes; ++q) {   // early exit at killer
                        float4 pl = pl4[q];               // 64-lane broadcast
                        float dt = pl.x*px[j] + pl.y*py[j] + pl.z*pz[j] - pl.w;
                        if (dt >= EPS_SEP) { keep = false; break; }
                    }
                    if (keep) {
                        keepm |= (1u << j);
                        float p2 = px[j]*px[j] + py[j]*py[j] + pz[j]*pz[j];
                        float tp = tx*px[j] + ty*py[j] + tz*pz[j];
                        float d2 = t2 + p2 - 2.0f*tp;     // reference's exact form
                        if (d2 < dmin) { dmin = d2; imin = i; } // i ascending/thread
                    }
                }
            }
            mycnt += (int)__popc(keepm);
            if (build) {                                  // compact survivors
                int c = (int)__popc(keepm);
                int incl = c;
                #pragma unroll
                for (int off = 1; off < 64; off <<= 1) {
                    int o = __shfl_up(incl, off, 64);
                    if (lane >= off) incl += o;
                }
                const int excl = incl - c;
                const int tot  = __shfl(incl, 63, 64);
                int wb = 0;
                if (lane == 0) wb = atomicAdd(cnt, tot);
                wb = __shfl(wb, 0, 64);
                int pos = wb + excl;
                #pragma unroll
                for (int j = 0; j < PT; ++j) {
                    if ((keepm >> j) & 1u) {
                        if (pos < CAP) list[pos] = ib + j * BLOCK;
                        ++pos;
                    }
                }
            }
        }
        return finish(dmin, imin, mycnt);
    };

    // Block-wide list scan, slab-major (coalesced LDS reads), in-place
    // re-compaction. Safe: per segment, all reads complete (barrier) before
    // appends, and append positions stay strictly below any unread segment.
    auto scanB = [&](int count, float ax, float ay, float az, float b) -> int2 {
        if (tid == 0) cnt[0] = 0;
        __syncthreads();
        float dmin = INFINITY;
        int   imin = 0;
        const int per = BLOCK * PB;
        const int bsteps = (count + per - 1) / per;
        for (int s = 0; s < bsteps; ++s) {
            int jv[PB]; float d2v[PB];
            uint32_t keepm = 0;
            #pragma unroll
            for (int q = 0; q < PB; ++q) {
                const int e = s * per + q * BLOCK + tid;  // lane-stride 1 word
                if (e < count) {
                    const int j = list[e];
                    jv[q] = j;
                    const float* p = pc + 3 * (size_t)j;
                    float px = p[0], py = p[1], pz = p[2];
                    float dt = ax*px + ay*py + az*pz - b;
                    if (dt < EPS_SEP) {
                        keepm |= (1u << q);
                        float p2 = px*px + py*py + pz*pz;
                        float tp = tx*px + ty*py + tz*pz;
                        d2v[q] = t2 + p2 - 2.0f*tp;
                    }
                }
            }
            __syncthreads();                       // reads done before appends
            int c = (int)__popc(keepm);
            int incl = c;
            #pragma unroll
            for (int off = 1; off < 64; off <<= 1) {
                int o = __shfl_up(incl, off, 64);
                if (lane >= off) incl += o;
            }
            const int excl = incl - c;
            const int tot  = __shfl(incl, 63, 64);
            int wb = 0;
            if (lane == 0) wb = atomicAdd(cnt, tot);
            wb = __shfl(wb, 0, 64);
            int pos = wb + excl;
            #pragma unroll
            for (int q = 0; q < PB; ++q) {
                if ((keepm >> q) & 1u) {
                    list[pos] = jv[q];
                    // list order arbitrary -> lexicographic for exact ties
                    if (d2v[q] < dmin || (d2v[q] == dmin && jv[q] < imin)) {
                        dmin = d2v[q]; imin = jv[q];
                    }
                    ++pos;
                }
            }
        }
        __syncthreads();                           // all appends/atomics done
        float dd = dmin; int ii = imin;
        #pragma unroll
        for (int off = 32; off > 0; off >>= 1) {
            float od = __shfl_down(dd, off, 64);
            int   oi = __shfl_down(ii, off, 64);
            if (od < dd || (od == dd && oi < ii)) { dd = od; ii = oi; }
        }
        if (lane == 0) { red_d[wv] = dd; red_i[wv] = ii; }
        __syncthreads();
        if (wv == 0) {
            float bd = (lane < NW) ? red_d[lane] : INFINITY;
            int   bi = (lane < NW) ? red_i[lane] : 0;
            #pragma unroll
            for (int off = 8; off > 0; off >>= 1) {
                float od = __shfl_down(bd, off, 64);
                int   oi = __shfl_down(bi, off, 64);
                if (od < bd || (od == bd && oi < bi)) { bd = od; bi = oi; }
            }
            if (lane == 0) { bcast[0] = bi; bcast[1] = cnt[0]; }
        }
        __syncthreads();
        int2 r; r.x = bcast[0]; r.y = bcast[1];
        return r;
    };

    bool comp = false;
    int2 rc = scanFull(0, false);
    int idx = rc.x, count = rc.y;                  // count = N here

    for (int k = 0; k < MAX_ITERS; ++k) {
        // Solo tail: wave 0 finishes all remaining iterations barrier-free.
        if (comp && count <= SOLO_CAP) {
            if (wv != 0) return;                   // LDS lives until last wave exits
            for (; k < MAX_ITERS; ++k) {
                const float cx = pc[3*idx+0], cy = pc[3*idx+1], cz = pc[3*idx+2];
                const float vx = cx - tx, vy = cy - ty, vz = cz - tz;
                const float nrm = sqrtf(vx*vx + vy*vy + vz*vz);
                const float den = nrm + EPS_NORM;
                const float ax = vx / den, ay = vy / den, az = vz / den;
                const float b  = ax*cx + ay*cy + az*cz;
                if (count == 0) {                  // constant tail: bulk write
                    for (int q = lane; q < MAX_ITERS - k; q += 64) {
                        const int kk = k + q;
                        const size_t oa = ((size_t)kk * M + m) * 3;
                        out_a[oa+0] = ax; out_a[oa+1] = ay; out_a[oa+2] = az;
                        out_b[(size_t)kk * M + m] = b;
                    }
                    return;
                }
                if (lane == 0) {
                    const size_t oa = ((size_t)k * M + m) * 3;
                    out_a[oa+0] = ax; out_a[oa+1] = ay; out_a[oa+2] = az;
                    out_b[(size_t)k * M + m] = b;
                }
                if (k + 1 < MAX_ITERS) {
                    float dmin = INFINITY; int imin = 0; int wcur = 0;
                    for (int e0 = 0; e0 < count; e0 += 64) {
                        const int e = e0 + lane;
                        bool keep = false; int j = 0; float d2v = 0.f;
                        if (e < count) {
                            j = list[e];
                            const float* p = pc + 3 * (size_t)j;
                            float px = p[0], py = p[1], pz = p[2];
                            float dt = ax*px + ay*py + az*pz - b;
                            if (dt < EPS_SEP) {
                                keep = true;
                                float p2 = px*px + py*py + pz*pz;
                                float tp = tx*px + ty*py + tz*pz;
                                d2v = t2 + p2 - 2.0f*tp;
                            }
                        }
                        // wave-synchronous in-place compact: pos < wcur+64 <= e0+64,
                        // and chunk [e0,e0+64) is already in registers.
                        unsigned long long bal = __ballot(keep);
                        int pos = wcur + (int)__popcll(bal & ((1ull << lane) - 1ull));
                        if (keep) {
                            list[pos] = j;
                            if (d2v < dmin || (d2v == dmin && j < imin)) {
                                dmin = d2v; imin = j;
                            }
                        }
                        wcur += (int)__popcll(bal);
                    }
                    #pragma unroll
                    for (int off = 32; off > 0; off >>= 1) {
                        float od = __shfl_down(dmin, off, 64);
                        int   oi = __shfl_down(imin, off, 64);
                        if (od < dmin || (od == dmin && oi < imin)) { dmin = od; imin = oi; }
                    }
                    idx = __shfl(imin, 0, 64);
                    count = wcur;                  // uniform across lanes
                }
            }
            return;
        }

        const float cx = pc[3*idx+0], cy = pc[3*idx+1], cz = pc[3*idx+2];
        const float vx = cx - tx, vy = cy - ty, vz = cz - tz;
        const float nrm = sqrtf(vx*vx + vy*vy + vz*vz);
        const float den = nrm + EPS_NORM;
        const float ax = vx / den, ay = vy / den, az = vz / den;
        const float b  = ax*cx + ay*cy + az*cz;    // b = sum(a * closest)

        if (count == 0) {                          // constant tail: bulk write
            for (int q = tid; q < MAX_ITERS - k; q += BLOCK) {
                const int kk = k + q;
                const size_t oa = ((size_t)kk * M + m) * 3;
                out_a[oa+0] = ax; out_a[oa+1] = ay; out_a[oa+2] = az;
                out_b[(size_t)kk * M + m] = b;
            }
            return;
        }
        if (tid == 0) {
            const size_t oa = ((size_t)k * M + m) * 3;
            out_a[oa+0] = ax; out_a[oa+1] = ay; out_a[oa+2] = az;
            out_b[(size_t)k * M + m] = b;
            planes[4*k+0] = ax; planes[4*k+1] = ay;    // for scanFull re-tests
            planes[4*k+2] = az; planes[4*k+3] = b;     // (visible after its barrier)
        }
        if (k + 1 < MAX_ITERS) {                   // last update unobservable
            if (comp) {
                rc = scanB(count, ax, ay, az, b);
            } else {
                const bool build = (count <= 2 * CAP);
                rc = scanFull(k + 1, build);       // planes 0..k incl. newest
                if (build && rc.y <= CAP) comp = true;
            }
            idx = rc.x; count = rc.y;
        }
    }
}

extern "C" void kernel_launch(void* const* d_in, const int* in_sizes, int n_in,
                              void* d_out, int out_size, void* d_ws, size_t ws_size,
                              hipStream_t stream) {
    const float* pc = (const float*)d_in[0];
    const float* tg = (const float*)d_in[1];
    float* out = (float*)d_out;
    const int N = in_sizes[0] / 3;
    const int M = in_sizes[1] / 3;
    const int stepsA = (N + BLOCK * PT - 1) / (BLOCK * PT);
    const size_t planeB = (size_t)MAX_ITERS * 4 * sizeof(float);
    const size_t fixedB = NW * (2 * sizeof(int) + sizeof(float)) + 3 * sizeof(int);

    int CAP = 32768;                               // 128 KB list; total ~131 KB LDS
    size_t smem = planeB + (size_t)CAP * sizeof(int) + fixedB;
    if (hipFuncSetAttribute((const void*)convex_plane_kernel,
                            hipFuncAttributeMaxDynamicSharedMemorySize,
                            (int)smem) != hipSuccess) {
        CAP = 14336;                               // stay within default 64 KB
        smem = planeB + (size_t)CAP * sizeof(int) + fixedB;
    }
    convex_plane_kernel<<<M, BLOCK, smem, stream>>>(pc, tg, out, N, M, CAP, stepsA);
}

// Round 6
// 595.812 us; speedup vs baseline: 1.8755x; 1.8755x over previous
//
#include <hip/hip_runtime.h>
#include <stdint.h>
#include <math.h>

// Match numpy's non-fused multiply-add rounding in distance/plane tests:
// a wrong argmin (or a boundary-mask flip) cascades into an O(1) output error.
// R1-R5 passed with absmax 0.0 using exactly these expression forms — keep them.
#pragma clang fp contract(off)

#define BLOCK 1024
#define NW (BLOCK / 64)
#define PT 8                    // points per thread per full-scan step (slab-major)
#define PB 4                    // entries per thread per list-scan step (slab-major)
#define MAX_ITERS 50
#define SOLO_CAP 2048           // below this, wave 0 finishes alone (no barriers)
#define EPS_NORM 1e-8f
#define EPS_SEP (-1e-6f)

// One block per target. Survival state = LDS bitmask over N points (R3's
// proven representation; R5's plane-list retest was a serial divergent LDS
// chain and regressed 1.7x).
// Phase A: full-N scans, slab-major x8 (i = s*8192 + j*1024 + tid): coalesced
//          global loads (R4 lesson), 8 independent broadcast mask reads/thread,
//          mask written via 8 ballots (lanes 0/32). When the incoming count
//          fits 2*CAP the scan also compacts survivors into an LDS list
//          (shfl prefix-scan + 1 atomic/wave/step).
// Phase B: list-only scans (lane-stride-1 LDS reads: 2-way aliasing is free),
//          re-compacting in place (append positions provably stay below any
//          unread segment).
// Solo tail (verified R5): below SOLO_CAP survivors, waves 1-15 retire; wave 0
// runs all remaining iterations wave-synchronously, zero __syncthreads.
__global__ __launch_bounds__(BLOCK) void convex_plane_kernel(
    const float* __restrict__ pc, const float* __restrict__ tg,
    float* __restrict__ out, int N, int M, int CAP, int stepsA)
{
    extern __shared__ uint32_t smem[];
    const int tid  = threadIdx.x;
    const int lane = tid & 63;
    const int wv   = tid >> 6;
    const int m    = blockIdx.x;

    const int maskW = stepsA * (PT * BLOCK / 32);  // mask words
    uint32_t* mask  = smem;                        // [maskW]
    int*      list  = (int*)(smem + maskW);        // [CAP]
    float*    red_d = (float*)(list + CAP);        // [NW]
    int*      red_i = (int*)(red_d + NW);          // [NW]
    int*      cw    = red_i + NW;                  // [NW]
    int*      bcast = cw + NW;                     // [2] {argmin idx, count}
    int*      cnt   = bcast + 2;                   // [1] list-append cursor

    const float tx = tg[3*m+0], ty = tg[3*m+1], tz = tg[3*m+2];
    const float t2 = tx*tx + ty*ty + tz*tz;

    float* out_a = out;
    float* out_b = out + (size_t)MAX_ITERS * (size_t)M * 3;

    // cross-wave finish: lexicographic (d2,idx) argmin + count sum; {idx,count}
    // returned to ALL threads via barrier-protected bcast (race-safe).
    auto finish = [&](float dmin, int imin, int mycnt, bool cntFromCursor) -> int2 {
        #pragma unroll
        for (int off = 32; off > 0; off >>= 1) {
            float od = __shfl_down(dmin, off, 64);
            int   oi = __shfl_down(imin, off, 64);
            int   oc = __shfl_down(mycnt, off, 64);
            if (od < dmin || (od == dmin && oi < imin)) { dmin = od; imin = oi; }
            mycnt += oc;
        }
        if (lane == 0) { red_d[wv] = dmin; red_i[wv] = imin; cw[wv] = mycnt; }
        __syncthreads();
        if (wv == 0) {
            float bd = (lane < NW) ? red_d[lane] : INFINITY;
            int   bi = (lane < NW) ? red_i[lane] : 0;
            int   c  = (lane < NW) ? cw[lane]    : 0;
            #pragma unroll
            for (int off = 8; off > 0; off >>= 1) {
                float od = __shfl_down(bd, off, 64);
                int   oi = __shfl_down(bi, off, 64);
                int   oc = __shfl_down(c,  off, 64);
                if (od < bd || (od == bd && oi < bi)) { bd = od; bi = oi; }
                c += oc;
            }
            if (lane == 0) { bcast[0] = bi; bcast[1] = cntFromCursor ? cnt[0] : c; }
        }
        __syncthreads();
        int2 r; r.x = bcast[0]; r.y = bcast[1];
        return r;
    };

    // Phase A: full-N scan, PT points/thread, slab-major.
    // mode 0: all live, no plane test, no mask write (initial argmin)
    // mode 1: all live, test plane, write mask (k=0 cut; mask uninitialized)
    // mode 2: read mask, test plane, write mask
    auto scanA = [&](int mode, bool build,
                     float ax, float ay, float az, float b) -> int2 {
        if (tid == 0) cnt[0] = 0;
        __syncthreads();
        float dmin = INFINITY;
        int   imin = 0;
        int   mycnt = 0;
        for (int s = 0; s < stepsA; ++s) {
            const int ib    = s * PT * BLOCK + tid;
            const int wbase = s * (PT * BLOCK / 32);
            uint32_t live = 0;
            if (mode == 2) {
                #pragma unroll
                for (int j = 0; j < PT; ++j) {       // 8 independent broadcasts
                    uint32_t w = mask[wbase + j * (BLOCK / 32) + (tid >> 5)];
                    live |= ((w >> (tid & 31)) & 1u) << j;
                }
            } else {
                #pragma unroll
                for (int j = 0; j < PT; ++j)
                    if (ib + j * BLOCK < N) live |= (1u << j);
            }
            float px[PT], py[PT], pz[PT];
            #pragma unroll
            for (int j = 0; j < PT; ++j) {           // coalesced, issued up front
                if ((live >> j) & 1u) {
                    const float* p = pc + 3 * (size_t)(ib + j * BLOCK);
                    px[j] = p[0]; py[j] = p[1]; pz[j] = p[2];
                }
            }
            uint32_t keepm = 0;
            #pragma unroll
            for (int j = 0; j < PT; ++j) {
                if ((live >> j) & 1u) {
                    bool keep;
                    if (mode == 0) keep = true;
                    else {
                        float dt = ax*px[j] + ay*py[j] + az*pz[j] - b;
                        keep = (dt < EPS_SEP);       // !(dt >= EPS_SEP)
                    }
                    if (keep) {
                        keepm |= (1u << j);
                        float p2 = px[j]*px[j] + py[j]*py[j] + pz[j]*pz[j];
                        float tp = tx*px[j] + ty*py[j] + tz*pz[j];
                        float d2 = t2 + p2 - 2.0f*tp;    // reference's exact form
                        // per-thread i ascends over (s,j): strict < = first-index
                        if (d2 < dmin) { dmin = d2; imin = ib + j * BLOCK; }
                    }
                }
            }
            if (mode != 0) {
                #pragma unroll
                for (int j = 0; j < PT; ++j) {       // mask write: 2 lanes/wave/j
                    unsigned long long bal = __ballot(((keepm >> j) & 1u) != 0u);
                    const int widx = wbase + j * (BLOCK / 32) + (wv << 1);
                    if (lane == 0)       mask[widx]     = (uint32_t)bal;
                    else if (lane == 32) mask[widx + 1] = (uint32_t)(bal >> 32);
                }
            }
            mycnt += (int)__popc(keepm);
            if (build) {                             // compact survivors
                int c = (int)__popc(keepm);
                int incl = c;
                #pragma unroll
                for (int off = 1; off < 64; off <<= 1) {
                    int o = __shfl_up(incl, off, 64);
                    if (lane >= off) incl += o;
                }
                const int excl = incl - c;
                const int tot  = __shfl(incl, 63, 64);
                int wb = 0;
                if (lane == 0) wb = atomicAdd(cnt, tot);
                wb = __shfl(wb, 0, 64);
                int pos = wb + excl;
                #pragma unroll
                for (int j = 0; j < PT; ++j) {
                    if ((keepm >> j) & 1u) {
                        if (pos < CAP) list[pos] = ib + j * BLOCK;
                        ++pos;
                    }
                }
            }
        }
        return finish(dmin, imin, mycnt, false);
    };

    // Phase B: list scan, slab-major, in-place re-compaction. Safe: per
    // segment, all reads complete (barrier) before appends, and append
    // positions stay strictly below any unread segment.
    auto scanB = [&](int count, float ax, float ay, float az, float b) -> int2 {
        if (tid == 0) cnt[0] = 0;
        __syncthreads();
        float dmin = INFINITY;
        int   imin = 0;
        const int per = BLOCK * PB;
        const int bsteps = (count + per - 1) / per;
        for (int s = 0; s < bsteps; ++s) {
            int jv[PB]; float d2v[PB];
            uint32_t keepm = 0;
            #pragma unroll
            for (int q = 0; q < PB; ++q) {
                const int e = s * per + q * BLOCK + tid;   // lane-stride 1
                if (e < count) {
                    const int j = list[e];
                    jv[q] = j;
                    const float* p = pc + 3 * (size_t)j;
                    float px = p[0], py = p[1], pz = p[2];
                    float dt = ax*px + ay*py + az*pz - b;
                    if (dt < EPS_SEP) {
                        keepm |= (1u << q);
                        float p2 = px*px + py*py + pz*pz;
                        float tp = tx*px + ty*py + tz*pz;
                        d2v[q] = t2 + p2 - 2.0f*tp;
                    }
                }
            }
            __syncthreads();                         // reads done before appends
            int c = (int)__popc(keepm);
            int incl = c;
            #pragma unroll
            for (int off = 1; off < 64; off <<= 1) {
                int o = __shfl_up(incl, off, 64);
                if (lane >= off) incl += o;
            }
            const int excl = incl - c;
            const int tot  = __shfl(incl, 63, 64);
            int wb = 0;
            if (lane == 0) wb = atomicAdd(cnt, tot);
            wb = __shfl(wb, 0, 64);
            int pos = wb + excl;
            #pragma unroll
            for (int q = 0; q < PB; ++q) {
                if ((keepm >> q) & 1u) {
                    list[pos] = jv[q];
                    // list order arbitrary -> lexicographic for exact ties
                    if (d2v[q] < dmin || (d2v[q] == dmin && jv[q] < imin)) {
                        dmin = d2v[q]; imin = jv[q];
                    }
                    ++pos;
                }
            }
        }
        __syncthreads();                             // all appends/atomics done
        return finish(dmin, imin, 0, true);          // count from cursor
    };

    bool comp = false;
    int2 rc = scanA(0, false, 0.f, 0.f, 0.f, 0.f);
    int idx = rc.x, count = rc.y;                    // count = N here

    for (int k = 0; k < MAX_ITERS; ++k) {
        // Solo tail (verified R5): wave 0 finishes barrier-free.
        if (comp && count <= SOLO_CAP) {
            if (wv != 0) return;                     // LDS persists while any wave lives
            for (; k < MAX_ITERS; ++k) {
                const float cx = pc[3*idx+0], cy = pc[3*idx+1], cz = pc[3*idx+2];
                const float vx = cx - tx, vy = cy - ty, vz = cz - tz;
                const float nrm = sqrtf(vx*vx + vy*vy + vz*vz);
                const float den = nrm + EPS_NORM;
                const float ax = vx / den, ay = vy / den, az = vz / den;
                const float b  = ax*cx + ay*cy + az*cz;
                if (count == 0) {                    // constant tail: bulk write
                    for (int q = lane; q < MAX_ITERS - k; q += 64) {
                        const int kk = k + q;
                        const size_t oa = ((size_t)kk * M + m) * 3;
                        out_a[oa+0] = ax; out_a[oa+1] = ay; out_a[oa+2] = az;
                        out_b[(size_t)kk * M + m] = b;
                    }
                    return;
                }
                if (lane == 0) {
                    const size_t oa = ((size_t)k * M + m) * 3;
                    out_a[oa+0] = ax; out_a[oa+1] = ay; out_a[oa+2] = az;
                    out_b[(size_t)k * M + m] = b;
                }
                if (k + 1 < MAX_ITERS) {
                    float dmin = INFINITY; int imin = 0; int wcur = 0;
                    for (int e0 = 0; e0 < count; e0 += 64) {
                        const int e = e0 + lane;
                        bool keep = false; int j = 0; float d2v = 0.f;
                        if (e < count) {
                            j = list[e];
                            const float* p = pc + 3 * (size_t)j;
                            float px = p[0], py = p[1], pz = p[2];
                            float dt = ax*px + ay*py + az*pz - b;
                            if (dt < EPS_SEP) {
                                keep = true;
                                float p2 = px*px + py*py + pz*pz;
                                float tp = tx*px + ty*py + tz*pz;
                                d2v = t2 + p2 - 2.0f*tp;
                            }
                        }
                        // in-place compact: pos < wcur+64 <= e0+64, and chunk
                        // [e0,e0+64) is already in registers.
                        unsigned long long bal = __ballot(keep);
                        int pos = wcur + (int)__popcll(bal & ((1ull << lane) - 1ull));
                        if (keep) {
                            list[pos] = j;
                            if (d2v < dmin || (d2v == dmin && j < imin)) {
                                dmin = d2v; imin = j;
                            }
                        }
                        wcur += (int)__popcll(bal);
                    }
                    #pragma unroll
                    for (int off = 32; off > 0; off >>= 1) {
                        float od = __shfl_down(dmin, off, 64);
                        int   oi = __shfl_down(imin, off, 64);
                        if (od < dmin || (od == dmin && oi < imin)) { dmin = od; imin = oi; }
                    }
                    idx = __shfl(imin, 0, 64);
                    count = wcur;                    // uniform across lanes
                }
            }
            return;
        }

        const float cx = pc[3*idx+0], cy = pc[3*idx+1], cz = pc[3*idx+2];
        const float vx = cx - tx, vy = cy - ty, vz = cz - tz;
        const float nrm = sqrtf(vx*vx + vy*vy + vz*vz);
        const float den = nrm + EPS_NORM;
        const float ax = vx / den, ay = vy / den, az = vz / den;
        const float b  = ax*cx + ay*cy + az*cz;      // b = sum(a * closest)

        if (count == 0) {                            // constant tail: bulk write
            for (int q = tid; q < MAX_ITERS - k; q += BLOCK) {
                const int kk = k + q;
                const size_t oa = ((size_t)kk * M + m) * 3;
                out_a[oa+0] = ax; out_a[oa+1] = ay; out_a[oa+2] = az;
                out_b[(size_t)kk * M + m] = b;
            }
            return;
        }
        if (tid == 0) {
            const size_t oa = ((size_t)k * M + m) * 3;
            out_a[oa+0] = ax; out_a[oa+1] = ay; out_a[oa+2] = az;
            out_b[(size_t)k * M + m] = b;
        }
        if (k + 1 < MAX_ITERS) {                     // last update unobservable
            if (comp) {
                rc = scanB(count, ax, ay, az, b);
            } else {
                const bool build = (count <= 2 * CAP);
                rc = scanA(k == 0 ? 1 : 2, build, ax, ay, az, b);
                if (build && rc.y <= CAP) comp = true;
            }
            idx = rc.x; count = rc.y;
        }
    }
}

extern "C" void kernel_launch(void* const* d_in, const int* in_sizes, int n_in,
                              void* d_out, int out_size, void* d_ws, size_t ws_size,
                              hipStream_t stream) {
    const float* pc = (const float*)d_in[0];
    const float* tg = (const float*)d_in[1];
    float* out = (float*)d_out;
    const int N = in_sizes[0] / 3;
    const int M = in_sizes[1] / 3;
    const int stepsA = (N + BLOCK * PT - 1) / (BLOCK * PT);
    const size_t maskB  = (size_t)stepsA * (PT * BLOCK / 32) * sizeof(uint32_t);
    const size_t fixedB = NW * (2 * sizeof(int) + sizeof(float)) + 3 * sizeof(int);

    int CAP = 32768;                                 // 128 KB list; total ~157 KB LDS
    size_t smem = maskB + (size_t)CAP * sizeof(int) + fixedB;
    if (hipFuncSetAttribute((const void*)convex_plane_kernel,
                            hipFuncAttributeMaxDynamicSharedMemorySize,
                            (int)smem) != hipSuccess) {
        CAP = 8192;                                  // stay within default 64 KB
        smem = maskB + (size_t)CAP * sizeof(int) + fixedB;
    }
    convex_plane_kernel<<<M, BLOCK, smem, stream>>>(pc, tg, out, N, M, CAP, stepsA);
}